// Round 5
// baseline (1616.558 us; speedup 1.0000x reference)
//
#include <hip/hip_runtime.h>
#include <cstdint>
#include <cstddef>

#define IN_CH 256
#define OUT_CH 128
#define NEG_SLOPE 0.2f
#define EPS 1e-16f

#define BK_SHIFT 7               // 128 dst nodes per bucket
#define BK_NODES 128
#define NB_MAX 1024              // max buckets (N <= 131072)
#define NBK 1024                 // partition/count blocks

typedef __attribute__((ext_vector_type(8))) short bf16x8;
typedef __attribute__((ext_vector_type(4))) float f32x4;

__device__ __forceinline__ unsigned short f2bf(float f) {
    unsigned int u = __float_as_uint(f);
    return (unsigned short)((u + 0x7fffu + ((u >> 16) & 1u)) >> 16);
}
__device__ __forceinline__ float bf_lo(unsigned int v) { return __uint_as_float(v << 16); }
__device__ __forceinline__ float bf_hi(unsigned int v) { return __uint_as_float(v & 0xffff0000u); }
__device__ __forceinline__ float lrelu(float x) { return (x > 0.f) ? x : x * NEG_SLOPE; }

// ---------------- one-time: w [256][128] f32 -> wt [128][256] bf16 (transposed) ----------------
__global__ __launch_bounds__(256) void convert_w_kernel(const float* __restrict__ w,
                                                        unsigned short* __restrict__ wt)
{
    const int n = blockIdx.x;
    const int k = threadIdx.x;
    wt[(size_t)n * IN_CH + k] = f2bf(w[(size_t)k * OUT_CH + n]);
}

// ---------------- MFMA GEMM body: 64 rows x 128 cols per block, no LDS ----------------
__device__ __forceinline__ void gemm_body(
    int bid, const float* __restrict__ x, const unsigned short* __restrict__ wt,
    const float* __restrict__ att_s, const float* __restrict__ att_d,
    unsigned short* __restrict__ xpb, float* __restrict__ asrc, float* __restrict__ adst,
    int M)
{
    const int tid  = threadIdx.x;
    const int wv   = tid >> 6;
    const int lane = tid & 63;
    const int lm   = lane & 15;
    const int quad = lane >> 4;
    const int arow = bid * 64 + wv * 16 + lm;
    const bool av  = arow < M;
    const float* xrow = x + (size_t)arow * IN_CH + quad * 8;

    f32x4 acc[8];
#pragma unroll
    for (int t = 0; t < 8; ++t) acc[t] = (f32x4){0.f, 0.f, 0.f, 0.f};

#pragma unroll
    for (int kk = 0; kk < 8; ++kk) {
        const int k0 = kk * 32;
        bf16x8 af = {0, 0, 0, 0, 0, 0, 0, 0};
        if (av) {
            float4 a0 = *(const float4*)(xrow + k0);
            float4 a1 = *(const float4*)(xrow + k0 + 4);
            af[0] = (short)f2bf(a0.x); af[1] = (short)f2bf(a0.y);
            af[2] = (short)f2bf(a0.z); af[3] = (short)f2bf(a0.w);
            af[4] = (short)f2bf(a1.x); af[5] = (short)f2bf(a1.y);
            af[6] = (short)f2bf(a1.z); af[7] = (short)f2bf(a1.w);
        }
#pragma unroll
        for (int t = 0; t < 8; ++t) {
            bf16x8 bf = *(const bf16x8*)(wt + (size_t)(16 * t + lm) * IN_CH + k0 + quad * 8);
            acc[t] = __builtin_amdgcn_mfma_f32_16x16x32_bf16(af, bf, acc[t], 0, 0, 0);
        }
    }

    float asw[8], adw[8];
#pragma unroll
    for (int t = 0; t < 8; ++t) {
        asw[t] = att_s[16 * t + lm];
        adw[t] = att_d[16 * t + lm];
    }
#pragma unroll
    for (int r = 0; r < 4; ++r) {
        const int orow = bid * 64 + wv * 16 + quad * 4 + r;
        if (orow < M) {
            float ps = 0.f, pd = 0.f;
            unsigned short* xr = xpb + (size_t)orow * OUT_CH + lm;
#pragma unroll
            for (int t = 0; t < 8; ++t) {
                float v = acc[t][r];
                xr[16 * t] = f2bf(v);
                ps += v * asw[t];
                pd += v * adw[t];
            }
#pragma unroll
            for (int m = 1; m < 16; m <<= 1) {
                ps += __shfl_xor(ps, m, 16);
                pd += __shfl_xor(pd, m, 16);
            }
            if (lm == 0) { asrc[orow] = ps; adst[orow] = pd; }
        }
    }
}

// count body: LDS histogram over coarse buckets, coalesced write bh[blk][bucket]
__device__ __forceinline__ void count_body(
    int blk, const int* __restrict__ src, const int* __restrict__ dst,
    int* __restrict__ bh, int E, int NB, int EPB)
{
    __shared__ int cnt[NB_MAX];
    for (int b = threadIdx.x; b < NB; b += 256) cnt[b] = 0;
    __syncthreads();
    const int e0 = blk * EPB;
    const int e1 = min(e0 + EPB, E);
    for (int e = e0 + threadIdx.x; e < e1; e += 256) {
        int s = src[e], d = dst[e];
        if (s != d) atomicAdd(&cnt[d >> BK_SHIFT], 1);
    }
    __syncthreads();
    int* row = bh + (size_t)blk * NB;
    for (int b = threadIdx.x; b < NB; b += 256) row[b] = cnt[b];
}

__global__ __launch_bounds__(256) void fused_gemm_count_kernel(
    const float* __restrict__ x, const unsigned short* __restrict__ wt,
    const float* __restrict__ att_s, const float* __restrict__ att_d,
    unsigned short* __restrict__ xpb, float* __restrict__ asrc, float* __restrict__ adst,
    int M,
    const int* __restrict__ src, const int* __restrict__ dst,
    int* __restrict__ bh, int E, int NB, int EPB)
{
    if ((int)blockIdx.x < NBK)
        count_body(blockIdx.x, src, dst, bh, E, NB, EPB);
    else
        gemm_body(blockIdx.x - NBK, x, wt, att_s, att_d, xpb, asrc, adst, M);
}

// per-bucket scan over the NBK block counts: escan[b][blk] (exclusive), btot[b]
__global__ __launch_bounds__(256) void scan_blocks_kernel(
    const int* __restrict__ bh, int* __restrict__ escan, int* __restrict__ btot, int NB)
{
    __shared__ int sh[256];
    const int b = blockIdx.x;
    const int t = threadIdx.x;
    int v[4];
#pragma unroll
    for (int i = 0; i < 4; ++i)
        v[i] = bh[(size_t)(4 * t + i) * NB + b];
    int psum = (v[0] + v[1]) + (v[2] + v[3]);
    sh[t] = psum;
    __syncthreads();
    for (int off = 1; off < 256; off <<= 1) {
        int u = (t >= off) ? sh[t - off] : 0;
        __syncthreads();
        sh[t] += u;
        __syncthreads();
    }
    int run = (t == 0) ? 0 : sh[t - 1];
    int* erow = escan + (size_t)b * NBK;
#pragma unroll
    for (int i = 0; i < 4; ++i) {
        erow[4 * t + i] = run;
        run += v[i];
    }
    if (t == 255) btot[b] = run;
}

// exclusive scan of bucket totals -> bbase[0..NB], bbase[NB] = total
__global__ __launch_bounds__(256) void bucket_base_kernel(
    const int* __restrict__ btot, int* __restrict__ bbase, int NB)
{
    __shared__ int sh[256];
    const int t = threadIdx.x;
    int v[4];
#pragma unroll
    for (int i = 0; i < 4; ++i) {
        int idx = 4 * t + i;
        v[i] = (idx < NB) ? btot[idx] : 0;
    }
    int psum = (v[0] + v[1]) + (v[2] + v[3]);
    sh[t] = psum;
    __syncthreads();
    for (int off = 1; off < 256; off <<= 1) {
        int u = (t >= off) ? sh[t - off] : 0;
        __syncthreads();
        sh[t] += u;
        __syncthreads();
    }
    int run = (t == 0) ? 0 : sh[t - 1];
#pragma unroll
    for (int i = 0; i < 4; ++i) {
        int idx = 4 * t + i;
        if (idx < NB) bbase[idx] = run;
        run += v[i];
    }
    if (t == 255) bbase[NB] = run;
}

// partition: place each edge into its bucket region (atomic-free global placement:
// base from scans, uniqueness from LDS counter), payload = (dlocal | s<<7, ex)
__global__ __launch_bounds__(256) void partition_kernel(
    const int* __restrict__ src, const int* __restrict__ dst,
    const float* __restrict__ asrc, const float* __restrict__ adst,
    const int* __restrict__ bbase, const int* __restrict__ escan,
    int2* __restrict__ part, int E, int NB, int EPB)
{
    __shared__ int lstart[NB_MAX];
    const int blk = blockIdx.x;
    for (int b = threadIdx.x; b < NB; b += 256)
        lstart[b] = bbase[b] + escan[(size_t)b * NBK + blk];
    __syncthreads();
    const int e0 = blk * EPB;
    const int e1 = min(e0 + EPB, E);
    for (int e = e0 + threadIdx.x; e < e1; e += 256) {
        int s = src[e], d = dst[e];
        if (s == d) continue;
        float ex = __expf(lrelu(asrc[s] + adst[d]));
        int b = d >> BK_SHIFT;
        int slot = atomicAdd(&lstart[b], 1);
        part[slot] = make_int2((d & (BK_NODES - 1)) | (s << BK_SHIFT), __float_as_int(ex));
    }
}

// bucket aggregation: one block per bucket; acc[128 dst][128 ch] in LDS (64 KB).
// Per edge: wave-wide xp row gather (bf16 pair / lane), 2 LDS f32 atomics / lane
// (stride-2 addresses -> free 2-way banking). Epilogue adds self loop + normalizes.
__global__ __launch_bounds__(256) void bucket_aggregate_kernel(
    const unsigned short* __restrict__ xpb, const float* __restrict__ asrc,
    const float* __restrict__ adst, const int* __restrict__ bbase,
    const int2* __restrict__ part, const float* __restrict__ bias,
    float* __restrict__ out, int N)
{
    __shared__ float acc[BK_NODES * OUT_CH];
    __shared__ float den[BK_NODES];
    const int tid = threadIdx.x;
    {
        float4 z = make_float4(0.f, 0.f, 0.f, 0.f);
        float4* a4 = (float4*)acc;
        for (int i = tid; i < BK_NODES * OUT_CH / 4; i += 256) a4[i] = z;
        if (tid < BK_NODES) den[tid] = 0.f;
    }
    __syncthreads();

    const int b = blockIdx.x;
    const int ebeg = bbase[b], eend = bbase[b + 1];
    const int wv = tid >> 6, lane = tid & 63;
    const unsigned int* xpw = (const unsigned int*)xpb;

    for (int e0 = ebeg + wv * 8; e0 < eend; e0 += 32) {
        const int m = min(8, eend - e0);
        int2 pl[8];
        unsigned int v[8];
#pragma unroll
        for (int u = 0; u < 8; ++u)
            if (u < m) pl[u] = part[e0 + u];
#pragma unroll
        for (int u = 0; u < 8; ++u)
            if (u < m) v[u] = xpw[(size_t)(pl[u].x >> BK_SHIFT) * 64 + lane];
#pragma unroll
        for (int u = 0; u < 8; ++u)
            if (u < m) {
                const float ex = __int_as_float(pl[u].y);
                const int dl = pl[u].x & (BK_NODES - 1);
                atomicAdd(&acc[dl * OUT_CH + 2 * lane],     ex * bf_lo(v[u]));
                atomicAdd(&acc[dl * OUT_CH + 2 * lane + 1], ex * bf_hi(v[u]));
                if (lane == 0) atomicAdd(&den[dl], ex);
            }
    }
    __syncthreads();

    // epilogue: thread t handles dl = t>>1, channel half = (t&1)*64
    const int dl = tid >> 1;
    const int half = tid & 1;
    const int n = b * BK_NODES + dl;
    if (n < N) {
        const float exs = __expf(lrelu(asrc[n] + adst[n]));
        const float inv = 1.f / (den[dl] + exs + EPS);
        const float* arow = acc + dl * OUT_CH + half * 64;
        const unsigned int* xrow = xpw + (size_t)n * 64 + half * 32;
        float* orow = out + (size_t)n * OUT_CH + half * 64;
        const float* brow = bias + half * 64;
#pragma unroll
        for (int j = 0; j < 32; ++j) {
            unsigned int u = xrow[j];
            float c0 = arow[2 * j]     + exs * bf_lo(u);
            float c1 = arow[2 * j + 1] + exs * bf_hi(u);
            orow[2 * j]     = c0 * inv + brow[2 * j];
            orow[2 * j + 1] = c1 * inv + brow[2 * j + 1];
        }
    }
}

// ---------------- launch ----------------
extern "C" void kernel_launch(void* const* d_in, const int* in_sizes, int n_in,
                              void* d_out, int out_size, void* d_ws, size_t ws_size,
                              hipStream_t stream)
{
    const float* x     = (const float*)d_in[0];
    const int*   ei    = (const int*)d_in[1];
    const float* w     = (const float*)d_in[2];
    const float* att_s = (const float*)d_in[3];
    const float* att_d = (const float*)d_in[4];
    const float* bias  = (const float*)d_in[5];
    float* out = (float*)d_out;

    const int N = in_sizes[0] / IN_CH;
    const int E = in_sizes[1] / 2;
    const int* src = ei;
    const int* dst = ei + E;

    const int NB  = (N + BK_NODES - 1) >> BK_SHIFT;   // 782 for N=100000
    const int EPB = (E + NBK - 1) / NBK;

    char* p = (char*)d_ws;
    auto take = [&](size_t bytes) { char* q = p; p += (bytes + 255) & ~size_t(255); return q; };
    unsigned short* xpb  = (unsigned short*)take((size_t)N * OUT_CH * 2);
    unsigned short* wt   = (unsigned short*)take((size_t)OUT_CH * IN_CH * 2);
    float* asrc  = (float*)take((size_t)N * 4);
    float* adst  = (float*)take((size_t)N * 4);
    int*   bh    = (int*)take((size_t)NBK * NB * 4);
    int*   escan = (int*)take((size_t)NB * NBK * 4);
    int*   btot  = (int*)take((size_t)NB * 4);
    int*   bbase = (int*)take((size_t)(NB + 1) * 4);
    int2*  part  = (int2*)take((size_t)E * 8);

    convert_w_kernel<<<OUT_CH, IN_CH, 0, stream>>>(w, wt);

    const int gemm_blocks = (N + 63) / 64;
    fused_gemm_count_kernel<<<NBK + gemm_blocks, 256, 0, stream>>>(
        x, wt, att_s, att_d, xpb, asrc, adst, N, src, dst, bh, E, NB, EPB);

    scan_blocks_kernel<<<NB, 256, 0, stream>>>(bh, escan, btot, NB);
    bucket_base_kernel<<<1, 256, 0, stream>>>(btot, bbase, NB);
    partition_kernel<<<NBK, 256, 0, stream>>>(src, dst, asrc, adst, bbase, escan, part, E, NB, EPB);
    bucket_aggregate_kernel<<<NB, 256, 0, stream>>>(xpb, asrc, adst, bbase, part, bias, out, N);
}